// Round 13
// baseline (196.886 us; speedup 1.0000x reference)
//
#include <hip/hip_runtime.h>
#include <hip/hip_bf16.h>

#define IDIM 256
#define GDIM 64
#define ODIM 512
#define KD   (IDIM * GDIM)
#define TILE_SHORTS (512 * 64)
#define WS_NEED ((size_t)512 * TILE_SHORTS * 2)   // 32 MB bf16 image

typedef __attribute__((ext_vector_type(8))) short bhalf8;
typedef __attribute__((ext_vector_type(4))) float fvec4;
typedef __attribute__((ext_vector_type(4))) unsigned uvec4;

#define INV2PI 0.15915494309189535f
#define AS1 __attribute__((address_space(1)))
#define AS3 __attribute__((address_space(3)))

static __device__ __forceinline__ short bf16b(float v) {
    __hip_bfloat16 hb = __float2bfloat16(v);
    short s; __builtin_memcpy(&s, &hb, 2); return s;
}
static __device__ __forceinline__ unsigned cvtpk(float lo, float hi) {
    unsigned r;
    asm("v_cvt_pk_bf16_f32 %0, %1, %2" : "=v"(r) : "v"(lo), "v"(hi));
    return r;
}

// advance one chain (cos or sin) by two Chebyshev steps
#define ADVP(A,B,C2) do { float _t = __builtin_fmaf((C2),(B),-(A)); (A)=(B); (B)=_t; \
                          _t = __builtin_fmaf((C2),(B),-(A)); (A)=(B); (B)=_t; } while (0)

// ws image, K-permuted [proven R5/R8/R9]: tile b = i*2+h, row o (512),
// slot z*32 + Q*8 + u -> coeff[z][o][i][16Q + 8h + u]; rows 128 B,
// XOR-swizzled 16B granules (^(o&7)<<4).
__global__ void prep_b(const float* __restrict__ coeffs, short* __restrict__ ws) {
    const int b = blockIdx.x;          // 512: i*2+h
    const int i = b >> 1, h = b & 1;
    const int o = threadIdx.x;         // 512
    short* dst = ws + ((size_t)b * 512 + o) * 64;
    const int swz = (o & 7) << 4;
#pragma unroll
    for (int j = 0; j < 8; ++j) {      // granule: z = j>>2, Q = j&3
        const int z = j >> 2, Qq = j & 3;
        const float* src = coeffs + ((size_t)z * ODIM + o) * KD
                         + (size_t)i * GDIM + 16 * Qq + 8 * h;
        fvec4 v0 = ((const fvec4*)src)[0];
        fvec4 v1 = ((const fvec4*)src)[1];
        bhalf8 pk;
#pragma unroll
        for (int u = 0; u < 4; ++u) { pk[u] = bf16b(v0[u]); pk[4 + u] = bf16b(v1[u]); }
        *(bhalf8*)((char*)dst + ((j * 16) ^ swz)) = pk;
    }
}

__global__ void bias_init(const float* __restrict__ bias, float* __restrict__ out) {
    int idx = blockIdx.x * 256 + threadIdx.x;
    fvec4 bv = ((const fvec4*)bias)[idx & 127];
    ((fvec4*)out)[idx] = bv;
}

// Fence proven R8/R9: asm drain of LDS-DMA (vmcnt) + sched pin + __syncthreads.
#define FENCE() do { asm volatile("s_waitcnt vmcnt(0) lgkmcnt(0)" ::: "memory"); \
                     __builtin_amdgcn_sched_barrier(0); \
                     __syncthreads(); } while (0)

// 1024 blocks = 32 mt x 4 ot x 8 ks, 4 blocks/CU. Block 256 thr = 4 waves in a
// 2x2 grid: wave owns 64 rows x 64 cols (acc[4][4]) -> B-read amplification 2x
// (8 ds_read_b128/tile/wave) vs R9's 4x. Chain-carry across the two h-tiles of
// each i; C2 held in registers (kC2[4]) so odd tiles read NO seed-panel data.
// Seed-panel refills run in odd tiles T==7 mod 8 (chunk (T+1)>>3): chunk c's
// last panel read is the seed at even tile 8c+6; FENCEs on both sides of tile
// 8c+7 make the refill race-free (R12's bug: fill at T==6 clobbered il=3 while
// tile 6/7 still read it).
template<int USE_WS>
__global__ void __launch_bounds__(256, 4)
fkan_gemm(const float* __restrict__ x, const float* __restrict__ coeffs,
          const short* __restrict__ wsb, float* __restrict__ out) {
    __shared__ __align__(16) short B_lds[2][128 * 64];   // 32 KB
    __shared__ float  sl_rev[4][128];                    // 2 KB
    __shared__ float2 sl_cs[4][128];                     // 4 KB

    const int bx = blockIdx.x;
    const int xcd = bx & 7, j = bx >> 3;
    const int lg  = xcd * 4 + (j & 3);
    const int mt  = j >> 2;
    const int ot  = lg >> 3, ks = lg & 7;
    const int row0 = mt * 128, col0 = ot * 128;
    const int i0 = ks * 32;

    const int t = threadIdx.x;
    const int lane = t & 63, wid = t >> 6;
    const int wave_m = wid & 1, wave_n = wid >> 1;   // 2 x 2
    const int kl  = (lane >> 4) * 16;
    const int msk = (lane & 7) << 4;
    const int rA0 = wave_m * 64 + (lane & 15);       // A row base (4 fm x 16)
    const int cB0 = wave_n * 64 + (lane & 15);       // B col base (4 fn x 16)
    const float m0f = (float)(16 * (lane >> 4) + 1);

    fvec4 acc[4][4];
#pragma unroll
    for (int a = 0; a < 4; ++a)
#pragma unroll
        for (int b = 0; b < 4; ++b) acc[a][b] = (fvec4)0.0f;

    // block-wide seed panel fill: (rev, cos x, sin x) per (row, i), 4 i's/chunk
    auto fill_sl = [&](int chunk) {
#pragma unroll
        for (int w2 = 0; w2 < 2; ++w2) {
            int idx = t + w2 * 256;           // 0..511
            int il2 = idx & 3, r2 = idx >> 2; // r2 0..127
            float xv = x[(size_t)(row0 + r2) * IDIM + i0 + chunk * 4 + il2];
            float rev = xv * INV2PI;
            float a = __builtin_amdgcn_fractf(rev);
            float2 cs;
            cs.x = __builtin_amdgcn_cosf(a);
            cs.y = __builtin_amdgcn_sinf(a);
            sl_rev[il2][r2] = rev;
            sl_cs[il2][r2] = cs;
        }
    };

    auto dmaB = [&](int T1) {
        const short* src = wsb + (size_t)(i0 * 2 + T1) * TILE_SHORTS
                         + (size_t)col0 * 64 + (size_t)t * 8;
        const int bsel = T1 & 1;
#pragma unroll
        for (int q = 0; q < 4; ++q)
            __builtin_amdgcn_global_load_lds(
                (const AS1 unsigned*)(src + q * 2048),
                (AS3 unsigned*)&B_lds[bsel][q * 2048 + wid * 512],
                16, 0, 0);
    };

    auto stage_fb = [&](int T1) {   // fallback staging (no ws)
        const int bsel = T1 & 1;
        const int i = i0 + (T1 >> 1), hh = T1 & 1;
        const int o = t >> 1, z = t & 1;
        char* drow = (char*)&B_lds[bsel][o * 64];
        const int swz = (o & 7) << 4;
#pragma unroll
        for (int Qq = 0; Qq < 4; ++Qq) {
            const float* src = coeffs + ((size_t)z * ODIM + col0 + o) * KD
                             + (size_t)i * GDIM + 16 * Qq + 8 * hh;
            fvec4 v0 = ((const fvec4*)src)[0];
            fvec4 v1 = ((const fvec4*)src)[1];
            bhalf8 pk;
#pragma unroll
            for (int u = 0; u < 4; ++u) { pk[u] = bf16b(v0[u]); pk[4 + u] = bf16b(v1[u]); }
            *(bhalf8*)(drow + ((z * 64 + Qq * 16) ^ swz)) = pk;
        }
    };

    // persistent chain state (statically indexed under full unroll)
    float kcA[4], kcB[4], ksA[4], ksB[4], kC2[4];

    // ---- prologue ----
    fill_sl(0);
    if (USE_WS) { dmaB(0); FENCE(); }
    else        { __syncthreads(); }

#pragma unroll 1
    for (int ii = 0; ii < 32; ++ii) {
        const int il = ii & 3;

        // ================= even tile T = 2*ii (h=0): seed =================
        {
            const int T = 2 * ii;
            if (USE_WS) {
                dmaB(T + 1);
                __builtin_amdgcn_sched_barrier(0);
            } else {
                stage_fb(T);
                __syncthreads();
            }
            const char* Bb = (const char*)&B_lds[0][0];

            // z=0: cos, seeded from panel (the ONLY panel reads, chunk = ii>>2)
            {
                bhalf8 bq[4];
#pragma unroll
                for (int fn = 0; fn < 4; ++fn)
                    bq[fn] = *(const bhalf8*)(Bb +
                        (size_t)(cB0 + fn * 16) * 128 + (kl ^ msk));
#pragma unroll
                for (int fm = 0; fm < 4; ++fm) {
                    const int rr = rA0 + fm * 16;
                    float rev = sl_rev[il][rr];
                    float2 cs1 = sl_cs[il][rr];
                    float C2x = cs1.x + cs1.x;
                    float a0 = __builtin_amdgcn_fractf(rev * m0f);
                    float c0 = __builtin_amdgcn_cosf(a0);
                    float s0 = __builtin_amdgcn_sinf(a0);
                    float cBv = __builtin_fmaf(c0, cs1.x, -(s0 * cs1.y));
                    float sBv = __builtin_fmaf(s0, cs1.x,  c0 * cs1.y);
                    uvec4 u; u[0] = cvtpk(c0, cBv);
                    float A = c0, B = cBv;
                    ADVP(A, B, C2x); u[1] = cvtpk(A, B);
                    ADVP(A, B, C2x); u[2] = cvtpk(A, B);
                    ADVP(A, B, C2x); u[3] = cvtpk(A, B);
                    kcA[fm] = A; kcB[fm] = B; ksA[fm] = s0; ksB[fm] = sBv; kC2[fm] = C2x;
                    bhalf8 af = __builtin_bit_cast(bhalf8, u);
                    __builtin_amdgcn_s_setprio(1);
#pragma unroll
                    for (int fn = 0; fn < 4; ++fn)
                        acc[fm][fn] = __builtin_amdgcn_mfma_f32_16x16x32_bf16(
                            af, bq[fn], acc[fm][fn], 0, 0, 0);
                    __builtin_amdgcn_s_setprio(0);
                }
            }
            // z=1: sin, fresh from seeded state (register C2)
            {
                bhalf8 bq[4];
#pragma unroll
                for (int fn = 0; fn < 4; ++fn)
                    bq[fn] = *(const bhalf8*)(Bb +
                        (size_t)(cB0 + fn * 16) * 128 + ((64 + kl) ^ msk));
#pragma unroll
                for (int fm = 0; fm < 4; ++fm) {
                    float C2x = kC2[fm];
                    float A = ksA[fm], B = ksB[fm];
                    uvec4 u; u[0] = cvtpk(A, B);
                    ADVP(A, B, C2x); u[1] = cvtpk(A, B);
                    ADVP(A, B, C2x); u[2] = cvtpk(A, B);
                    ADVP(A, B, C2x); u[3] = cvtpk(A, B);
                    ksA[fm] = A; ksB[fm] = B;
                    bhalf8 af = __builtin_bit_cast(bhalf8, u);
                    __builtin_amdgcn_s_setprio(1);
#pragma unroll
                    for (int fn = 0; fn < 4; ++fn)
                        acc[fm][fn] = __builtin_amdgcn_mfma_f32_16x16x32_bf16(
                            af, bq[fn], acc[fm][fn], 0, 0, 0);
                    __builtin_amdgcn_s_setprio(0);
                }
            }
            if (USE_WS) FENCE(); else __syncthreads();
        }

        // ================= odd tile T = 2*ii+1 (h=1): continue, NO panel reads ===
        {
            const int T = 2 * ii + 1;
            if (USE_WS) {
                if ((T & 7) == 7 && T < 63) fill_sl((T + 1) >> 3);  // safe window
                if (T < 63) dmaB(T + 1);
                __builtin_amdgcn_sched_barrier(0);
            } else {
                if ((T & 7) == 7 && T < 63) fill_sl((T + 1) >> 3);
                stage_fb(T);
                __syncthreads();
            }
            const char* Bb = (const char*)&B_lds[1][0];

            // z=0: cos chain continue
            {
                bhalf8 bq[4];
#pragma unroll
                for (int fn = 0; fn < 4; ++fn)
                    bq[fn] = *(const bhalf8*)(Bb +
                        (size_t)(cB0 + fn * 16) * 128 + (kl ^ msk));
#pragma unroll
                for (int fm = 0; fm < 4; ++fm) {
                    float C2x = kC2[fm];
                    float A = kcA[fm], B = kcB[fm];
                    uvec4 u;
                    ADVP(A, B, C2x); u[0] = cvtpk(A, B);
                    ADVP(A, B, C2x); u[1] = cvtpk(A, B);
                    ADVP(A, B, C2x); u[2] = cvtpk(A, B);
                    ADVP(A, B, C2x); u[3] = cvtpk(A, B);
                    bhalf8 af = __builtin_bit_cast(bhalf8, u);
                    __builtin_amdgcn_s_setprio(1);
#pragma unroll
                    for (int fn = 0; fn < 4; ++fn)
                        acc[fm][fn] = __builtin_amdgcn_mfma_f32_16x16x32_bf16(
                            af, bq[fn], acc[fm][fn], 0, 0, 0);
                    __builtin_amdgcn_s_setprio(0);
                }
            }
            // z=1: sin chain continue
            {
                bhalf8 bq[4];
#pragma unroll
                for (int fn = 0; fn < 4; ++fn)
                    bq[fn] = *(const bhalf8*)(Bb +
                        (size_t)(cB0 + fn * 16) * 128 + ((64 + kl) ^ msk));
#pragma unroll
                for (int fm = 0; fm < 4; ++fm) {
                    float C2x = kC2[fm];
                    float A = ksA[fm], B = ksB[fm];
                    uvec4 u;
                    ADVP(A, B, C2x); u[0] = cvtpk(A, B);
                    ADVP(A, B, C2x); u[1] = cvtpk(A, B);
                    ADVP(A, B, C2x); u[2] = cvtpk(A, B);
                    ADVP(A, B, C2x); u[3] = cvtpk(A, B);
                    bhalf8 af = __builtin_bit_cast(bhalf8, u);
                    __builtin_amdgcn_s_setprio(1);
#pragma unroll
                    for (int fn = 0; fn < 4; ++fn)
                        acc[fm][fn] = __builtin_amdgcn_mfma_f32_16x16x32_bf16(
                            af, bq[fn], acc[fm][fn], 0, 0, 0);
                    __builtin_amdgcn_s_setprio(0);
                }
            }
            if (USE_WS) FENCE(); else __syncthreads();
        }
    }

    // epilogue: C/D layout col=lane&15, row=(lane>>4)*4+r
#pragma unroll
    for (int fm = 0; fm < 4; ++fm) {
#pragma unroll
        for (int fn = 0; fn < 4; ++fn) {
            int col = col0 + wave_n * 64 + fn * 16 + (lane & 15);
#pragma unroll
            for (int r = 0; r < 4; ++r) {
                int row = row0 + wave_m * 64 + fm * 16 + ((lane >> 4) * 4) + r;
                atomicAdd(&out[(size_t)row * ODIM + col], acc[fm][fn][r]);
            }
        }
    }
}

extern "C" void kernel_launch(void* const* d_in, const int* in_sizes, int n_in,
                              void* d_out, int out_size, void* d_ws, size_t ws_size,
                              hipStream_t stream) {
    (void)in_sizes; (void)n_in; (void)out_size;
    const float* x      = (const float*)d_in[0];
    const float* coeffs = (const float*)d_in[1];
    const float* bias   = (const float*)d_in[2];
    float* out = (float*)d_out;

    const bool use_ws = (ws_size >= WS_NEED) && (((uintptr_t)d_ws & 15) == 0);

    bias_init<<<dim3(2048), dim3(256), 0, stream>>>(bias, out);
    if (use_ws) {
        prep_b<<<dim3(512), dim3(512), 0, stream>>>(coeffs, (short*)d_ws);
        fkan_gemm<1><<<dim3(1024), dim3(256), 0, stream>>>(x, coeffs, (const short*)d_ws, out);
    } else {
        fkan_gemm<0><<<dim3(1024), dim3(256), 0, stream>>>(x, coeffs, nullptr, out);
    }
}